// Round 7
// baseline (224.958 us; speedup 1.0000x reference)
//
#include <hip/hip_runtime.h>
#include <math.h>

typedef unsigned short u16;
typedef unsigned int   u32;
typedef __attribute__((ext_vector_type(8))) short short8;
typedef __attribute__((ext_vector_type(4))) float f32x4;

#define HW 4096

// ws layout (float offsets). ws_size = 256 MiB.
#define OFS_XB   0ul          // 32768 x 512 bf16: [pixel][ch]; ch 0-255 = x, 256-511 = agg
#define OFS_W1B  8683520ul    // 256x256 bf16 folded embed weights [o][k]
#define OFS_W2B  8716288ul    // 256x512 bf16 folded enhance weights [o][k]
#define OFS_B1   8781824ul    // 256 fp32
#define OFS_B2   8782080ul    // 256 fp32
#define OFS_POOL 8782336ul    // 8*512 fp32 (atomic-accumulated means)
#define OFS_GATE 8786432ul    // 8*256
#define OFS_ENH  8788480ul    // 32768x256 bf16 enhanced

__device__ __forceinline__ u16 f2bf(float x) {
    union { float f; u32 u; } v; v.f = x;
    u32 r = v.u + 0x7fffu + ((v.u >> 16) & 1u);
    return (u16)(r >> 16);
}
__device__ __forceinline__ float bf2f(u16 h) {
    union { u32 u; float f; } v; v.u = ((u32)h) << 16;
    return v.f;
}
__device__ __forceinline__ void ld_g2l_16(u16* l, const u16* g) {
    __builtin_amdgcn_global_load_lds(
        (const __attribute__((address_space(1))) u32*)g,
        (__attribute__((address_space(3))) u32*)l,
        16, 0, 0);
}

// ---------------- cvt (+fused prep): zero-first, then weights, then x->xb ----------------
// Block 0..3: pool zero (FIRST so cvt atomics land after). 4..773: weight fold.
// 774..2821: cvt + x-pool.
__global__ __launch_bounds__(256) void k_cvt(
    const float* __restrict__ x, u16* __restrict__ xb, float* __restrict__ pool,
    const float* __restrict__ w1, const float* __restrict__ b1,
    const float* __restrict__ g1, const float* __restrict__ be1,
    const float* __restrict__ m1, const float* __restrict__ v1,
    const float* __restrict__ w2, const float* __restrict__ b2,
    const float* __restrict__ g2, const float* __restrict__ be2,
    const float* __restrict__ m2, const float* __restrict__ v2,
    u16* __restrict__ w1b, u16* __restrict__ w2b,
    float* __restrict__ b1f, float* __restrict__ b2f)
{
    __shared__ float tile[64][65];
    const int t = threadIdx.x;
    const int id = blockIdx.x;
    if (id < 4) {                            // pool zero (dispatched first)
        const float4 z = {0.f, 0.f, 0.f, 0.f};
        ((float4*)(pool + id * 1024))[t] = z;
        return;
    }
    if (id < 774) {                          // weight prep
        int idx = (id - 4) * 256 + t;
        if (idx < 65536) {
            int o = idx >> 8;
            float inv = g1[o] * rsqrtf(v1[o] + 1e-5f);
            w1b[idx] = f2bf(w1[idx] * inv);
        } else if (idx < 196608) {
            int j = idx - 65536;
            int o = j >> 9;
            float inv = g2[o] * rsqrtf(v2[o] + 1e-5f);
            w2b[j] = f2bf(w2[j] * inv);
        } else if (idx < 196864) {
            int o = idx - 196608;
            float inv = g1[o] * rsqrtf(v1[o] + 1e-5f);
            b1f[o] = b1[o] * inv + be1[o] - m1[o] * inv;
        } else if (idx < 197120) {
            int o = idx - 196864;
            float inv = g2[o] * rsqrtf(v2[o] + 1e-5f);
            b2f[o] = b2[o] * inv + be2[o] - m2[o] * inv;
        }
        return;
    }
    const int cid = id - 774;                // 0..2047
    const int pt = cid & 63, ct = (cid >> 6) & 3, b = cid >> 8;
    const float* src = x + (((size_t)(b * 256 + ct * 64)) << 12) + pt * 64;
#pragma unroll
    for (int i = 0; i < 16; ++i) {
        int idx = i * 256 + t;
        int cl = idx >> 6, pl = idx & 63;
        tile[cl][pl] = src[((size_t)cl << 12) + pl];
    }
    __syncthreads();
#pragma unroll
    for (int i = 0; i < 8; ++i) {
        int idx = i * 256 + t;
        int pl = idx >> 5, c2 = idx & 31;
        int cl = c2 * 2;
        u32 lo = f2bf(tile[cl][pl]);
        u32 hi = f2bf(tile[cl + 1][pl]);
        *(u32*)(xb + (((size_t)(b * 4096 + pt * 64 + pl)) << 9) + ct * 64 + cl) = lo | (hi << 16);
    }
    if (t < 64) {
        float s = 0.f;
#pragma unroll
        for (int i = 0; i < 64; ++i) s += tile[t][i];
        atomicAdd(&pool[(b << 9) + ct * 64 + t], s * (1.f / 4096.f));
    }
}

// ---------------- bf16 MFMA GEMM ----------------
// MODE 0: write feT[p][c] u16 (transposed, for k_simagg staging).
// MODE 1: write enh[b][c][p] u16 + fused SE-pool atomics.
template<int KIN, int MODE>
__global__ __launch_bounds__(256) void k_gemm(
    const u16* __restrict__ xb, const u16* __restrict__ Wb,
    const float* __restrict__ biasf, void* __restrict__ outp,
    float* __restrict__ poolp)
{
    __shared__ __align__(16) u16 Wl[4096];
    __shared__ __align__(16) u16 Xl[4096];
    __shared__ float sbias[128];
    const int t = threadIdx.x;
    const int lane = t & 63;
    const int wv = t >> 6;
    const int p_blk = blockIdx.y * 128;
    const int o_blk = blockIdx.x * 128;
    const int owg = (wv & 1) * 4;
    const int pwg = (wv >> 1) * 4;
    const int r16 = lane & 15, q = lane >> 4;
    if (t < 128) sbias[t] = biasf[o_blk + t];

    f32x4 acc[4][4];
#pragma unroll
    for (int i = 0; i < 4; ++i)
#pragma unroll
        for (int j = 0; j < 4; ++j) acc[i][j] = (f32x4){0.f, 0.f, 0.f, 0.f};

    for (int kc = 0; kc < KIN / 32; ++kc) {
        const int kk = kc * 32 + q * 8;
#pragma unroll
        for (int s = 0; s < 4; ++s) {
            const int bi = wv * 4 + s;
            const u16* g;
            u16* l;
            if (bi < 8) {
                g = Wb + (size_t)(o_blk + bi * 16 + r16) * KIN + kk;
                l = Wl + bi * 512;
            } else {
                g = xb + (((size_t)(p_blk + (bi - 8) * 16 + r16)) << 9) + kk;
                l = Xl + (bi - 8) * 512;
            }
            ld_g2l_16(l, g);
        }
        __syncthreads();
        short8 af[4], bf[4];
#pragma unroll
        for (int i = 0; i < 4; ++i) af[i] = *(const short8*)(Wl + (owg + i) * 512 + lane * 8);
#pragma unroll
        for (int j = 0; j < 4; ++j) bf[j] = *(const short8*)(Xl + (pwg + j) * 512 + lane * 8);
#pragma unroll
        for (int i = 0; i < 4; ++i)
#pragma unroll
            for (int j = 0; j < 4; ++j)
                acc[i][j] = __builtin_amdgcn_mfma_f32_16x16x32_bf16(af[i], bf[j], acc[i][j], 0, 0, 0);
        __syncthreads();
    }

    float bia[4][4];
#pragma unroll
    for (int i = 0; i < 4; ++i)
#pragma unroll
        for (int r = 0; r < 4; ++r) bia[i][r] = sbias[owg * 16 + i * 16 + q * 4 + r];
    const int bidx = p_blk >> 12;
    const int pin0 = (p_blk & 4095) + pwg * 16 + r16;
#pragma unroll
    for (int i = 0; i < 4; ++i) {
#pragma unroll
        for (int r = 0; r < 4; ++r) {
            const int o = o_blk + owg * 16 + i * 16 + q * 4 + r;
            float ps = 0.f;
#pragma unroll
            for (int j = 0; j < 4; ++j) {
                float v = fmaxf(acc[i][j][r] + bia[i][r], 0.f);
                if (MODE == 0) {      // feT[p][o]
                    const size_t p = (size_t)(p_blk + pwg * 16 + r16 + j * 16);
                    ((u16*)outp)[(p << 8) + o] = f2bf(v);
                } else {              // enh[b][o][pix]
                    const size_t oi = (((size_t)(bidx * 256 + o)) << 12) + pin0 + j * 16;
                    ((u16*)outp)[oi] = f2bf(v);
                }
                ps += v;
            }
            if (MODE == 1) {
                ps += __shfl_down(ps, 8, 16);
                ps += __shfl_down(ps, 4, 16);
                ps += __shfl_down(ps, 2, 16);
                ps += __shfl_down(ps, 1, 16);
                if (r16 == 0)
                    atomicAdd(&poolp[(bidx << 9) + 256 + o], ps * (1.f / 4096.f));
            }
        }
    }
}

// ---------------- fused sim + softmax + agg (block-local, no pd) ----------------
// Block (b, h, 32-px half). Phase1: stage feT 3x34x256 window packed [pos][c]
// (52KB, lane-linear => global_load_lds OK; c-contiguous => conflict-free b128).
// Compute nsq[102] + dot[9] per px (shuffle-reduce over 32 c-lanes), softmax
// with border masks. Phase2: re-stage x window (same LDS), aggregate, write
// bf16 to xb cols 256-511.
__global__ __launch_bounds__(256) void k_simagg(
    const u16* __restrict__ feT, const u16* __restrict__ xb, u16* __restrict__ xbo)
{
    __shared__ __align__(16) u16 st[104 * 256];   // 53248 B packed window
    __shared__ float nsq[102];
    __shared__ float dot9[32][9];
    __shared__ float ws9[9][32];
    const int t = threadIdx.x;
    const int id = blockIdx.x;                 // 1024 = b(8) x h(64) x half(2)
    const int half = id & 1, h = (id >> 1) & 63, b = id >> 7;
    const int w0 = half * 32;
    const int rows[3] = {h > 0 ? h - 1 : 0, h, h < 63 ? h + 1 : 63};
    const size_t pbase = (size_t)b * 4096;

    // ---- phase1 stage feT window: unit u = pos*32 + c-chunk ----
#pragma unroll
    for (int it = 0; it < 13; ++it) {
        const int u = it * 256 + t;            // 0..3327 (tail clamped)
        int pos = u >> 5; if (pos > 101) pos = 101;
        const int chunk = u & 31;
        const int r = pos / 34, wloc = pos - r * 34;
        int wg = w0 - 1 + wloc; wg = wg < 0 ? 0 : (wg > 63 ? 63 : wg);
        ld_g2l_16(st + u * 8, feT + ((pbase + rows[r] * 64 + wg) << 8) + chunk * 8);
    }
    __syncthreads();

    // ---- nsq for all 102 positions (32 c-lanes each, shuffle-reduced) ----
#pragma unroll 2
    for (int it = 0; it < 13; ++it) {
        const int u = it * 256 + t;
        int pos = u >> 5; const int cs = u & 31;
        const bool valid = pos <= 101; if (!valid) pos = 101;
        const short8 v = *(const short8*)(st + pos * 256 + cs * 8);
        float s = 0.f;
#pragma unroll
        for (int e = 0; e < 8; ++e) { const float f = bf2f((u16)v[e]); s = fmaf(f, f, s); }
        s += __shfl_xor(s, 1, 64);
        s += __shfl_xor(s, 2, 64);
        s += __shfl_xor(s, 4, 64);
        s += __shfl_xor(s, 8, 64);
        s += __shfl_xor(s, 16, 64);
        if (cs == 0 && valid) nsq[pos] = s;
    }

    // ---- dot[9] per center px; lanes = 32 c-chunks x 2 px-quads ----
    {
        const int lane = t & 63, wave = t >> 6;
        const int cs = lane & 31, wq = lane >> 5;
        const int c8 = cs * 8;
#pragma unroll
        for (int pi = 0; pi < 4; ++pi) {
            const int px = (wave * 2 + wq) * 4 + pi;            // 0..31
            const short8 cv = *(const short8*)(st + (34 + px + 1) * 256 + c8);
            float cf[8];
#pragma unroll
            for (int e = 0; e < 8; ++e) cf[e] = bf2f((u16)cv[e]);
            float d[9];
#pragma unroll
            for (int dr = 0; dr < 3; ++dr)
#pragma unroll
                for (int dj = 0; dj < 3; ++dj) {
                    const short8 nv = *(const short8*)(st + (dr * 34 + px + dj) * 256 + c8);
                    float a = 0.f;
#pragma unroll
                    for (int e = 0; e < 8; ++e) a = fmaf(cf[e], bf2f((u16)nv[e]), a);
                    d[dr * 3 + dj] = a;
                }
#pragma unroll
            for (int k = 0; k < 9; ++k) {
                float a = d[k];
                a += __shfl_xor(a, 1, 64);
                a += __shfl_xor(a, 2, 64);
                a += __shfl_xor(a, 4, 64);
                a += __shfl_xor(a, 8, 64);
                a += __shfl_xor(a, 16, 64);
                if (cs == 0) dot9[px][k] = a;
            }
        }
    }
    __syncthreads();

    // ---- phase2 stage x window (reuse st; old content dead) ----
#pragma unroll
    for (int it = 0; it < 13; ++it) {
        const int u = it * 256 + t;
        int pos = u >> 5; if (pos > 101) pos = 101;
        const int chunk = u & 31;
        const int r = pos / 34, wloc = pos - r * 34;
        int wg = w0 - 1 + wloc; wg = wg < 0 ? 0 : (wg > 63 ? 63 : wg);
        ld_g2l_16(st + u * 8, xb + ((pbase + rows[r] * 64 + wg) << 9) + chunk * 8);
    }
    // ---- softmax + border mask (t < 32), overlaps staging ----
    if (t < 32) {
        const int px = t;
        const int wgl = w0 + px;
        const float nc = sqrtf(nsq[34 + px + 1]);
        float s[9], mk[9];
#pragma unroll
        for (int di = -1; di <= 1; ++di)
#pragma unroll
            for (int dj = -1; dj <= 1; ++dj) {
                const int k = (di + 1) * 3 + (dj + 1);
                const int hn = h + di, wn = wgl + dj;
                const float mask = (hn >= 0 && hn < 64 && wn >= 0 && wn < 64) ? 1.f : 0.f;
                const float nk = nsq[(di + 1) * 34 + px + 1 + dj];
                mk[k] = mask;
                s[k] = mask * dot9[px][k] / (nc * sqrtf(nk) + 1e-7f);
            }
        float mx = s[0];
#pragma unroll
        for (int k = 1; k < 9; ++k) mx = fmaxf(mx, s[k]);
        float e[9], sum = 0.f;
#pragma unroll
        for (int k = 0; k < 9; ++k) { e[k] = expf(s[k] - mx); sum += e[k]; }
        const float rs = 1.f / sum;
#pragma unroll
        for (int k = 0; k < 9; ++k) ws9[k][px] = mk[k] * e[k] * rs;
    }
    __syncthreads();

    // ---- aggregate: units (px 32 x c-chunk 32), 4 per thread ----
#pragma unroll
    for (int it = 0; it < 4; ++it) {
        const int u = it * 256 + t;
        const int cs = u & 31, px = u >> 5;
        float acc[8] = {};
#pragma unroll
        for (int dr = 0; dr < 3; ++dr)
#pragma unroll
            for (int dj = 0; dj < 3; ++dj) {
                const float wk = ws9[dr * 3 + dj][px];
                const short8 nv = *(const short8*)(st + (dr * 34 + px + dj) * 256 + cs * 8);
#pragma unroll
                for (int e = 0; e < 8; ++e) acc[e] = fmaf(bf2f((u16)nv[e]), wk, acc[e]);
            }
        union { u16 a[8]; short8 v; } pk;
#pragma unroll
        for (int e = 0; e < 8; ++e) pk.a[e] = f2bf(acc[e]);
        *(short8*)(xbo + ((pbase + h * 64 + w0 + px) << 9) + 256 + cs * 8) = pk.v;
    }
}

// ---------------- SE-style gate MLP ----------------
__global__ __launch_bounds__(64) void k_mlp(
    const float* __restrict__ pool,
    const float* __restrict__ wg1, const float* __restrict__ bg1,
    const float* __restrict__ wg2, const float* __restrict__ bg2,
    float* __restrict__ gate)
{
    __shared__ float pl[512];
    __shared__ float hb[64];
    const int b = blockIdx.x, t = threadIdx.x;
    for (int i = t; i < 512; i += 64) pl[i] = pool[b * 512 + i];
    __syncthreads();
    float s = bg1[t];
    const float* wr = wg1 + t * 512;
    for (int c = 0; c < 512; ++c) s = fmaf(wr[c], pl[c], s);
    hb[t] = fmaxf(s, 0.f);
    __syncthreads();
#pragma unroll
    for (int rr = 0; rr < 4; ++rr) {
        const int o = t + rr * 64;
        float s2 = bg2[o];
        const float* w2 = wg2 + o * 64;
        for (int j = 0; j < 64; ++j) s2 = fmaf(w2[j], hb[j], s2);
        gate[b * 256 + o] = 1.f / (1.f + expf(-s2));
    }
}

// ---------------- final: out = x(bf16 from xb) + gate * enhanced(bf16) ----------------
__global__ __launch_bounds__(256) void k_final(
    const u16* __restrict__ xb, const u16* __restrict__ enh,
    const float* __restrict__ gate, float* __restrict__ out)
{
    const int t = threadIdx.x;
    const int id = blockIdx.x;               // 512 = 8 b x 64 groups
    const int b = id >> 6, rg = id & 63;
    const int w = t & 63, s = t >> 6;
    const int p = rg * 64 + w;
    const u16* xrow = xb + (((size_t)(b * 4096 + p)) << 9) + s * 64;
#pragma unroll 2
    for (int cc = 0; cc < 8; ++cc) {
        short8 xv = *(const short8*)(xrow + cc * 8);
#pragma unroll
        for (int u = 0; u < 8; ++u) {
            const int c = s * 64 + cc * 8 + u;
            const float gt = gate[(b << 8) + c];
            const size_t off = (((size_t)(b * 256 + c)) << 12) + p;
            out[off] = fmaf(gt, bf2f(enh[off]), bf2f((u16)xv[u]));
        }
    }
}

extern "C" void kernel_launch(void* const* d_in, const int* in_sizes, int n_in,
                              void* d_out, int out_size, void* d_ws, size_t ws_size,
                              hipStream_t stream)
{
    const float* x       = (const float*)d_in[0];
    const float* w_embed = (const float*)d_in[1];
    const float* b_embed = (const float*)d_in[2];
    const float* g1      = (const float*)d_in[3];
    const float* be1     = (const float*)d_in[4];
    const float* m1      = (const float*)d_in[5];
    const float* v1      = (const float*)d_in[6];
    const float* w_enh   = (const float*)d_in[7];
    const float* b_enh   = (const float*)d_in[8];
    const float* g2      = (const float*)d_in[9];
    const float* be2     = (const float*)d_in[10];
    const float* m2      = (const float*)d_in[11];
    const float* v2      = (const float*)d_in[12];
    const float* w_g1    = (const float*)d_in[13];
    const float* b_g1    = (const float*)d_in[14];
    const float* w_g2    = (const float*)d_in[15];
    const float* b_g2    = (const float*)d_in[16];
    float* ws  = (float*)d_ws;
    float* out = (float*)d_out;

    u16*   xb   = (u16*)(ws + OFS_XB);
    u16*   w1b  = (u16*)(ws + OFS_W1B);
    u16*   w2b  = (u16*)(ws + OFS_W2B);
    float* b1f  = ws + OFS_B1;
    float* b2f  = ws + OFS_B2;
    float* pool = ws + OFS_POOL;
    float* gate = ws + OFS_GATE;
    u16*   enh  = (u16*)(ws + OFS_ENH);
    u16*   feT  = (u16*)d_out;   // feT[p][c] bf16 in d_out; dead before k_final writes

    k_cvt<<<dim3(2822), dim3(256), 0, stream>>>(
        x, xb, pool,
        w_embed, b_embed, g1, be1, m1, v1,
        w_enh, b_enh, g2, be2, m2, v2, w1b, w2b, b1f, b2f);
    k_gemm<256, 0><<<dim3(2, 256), dim3(256), 0, stream>>>(xb, w1b, b1f, (void*)feT, nullptr);
    k_simagg<<<dim3(1024), dim3(256), 0, stream>>>(feT, xb, xb);
    k_gemm<512, 1><<<dim3(2, 256), dim3(256), 0, stream>>>(xb, w2b, b2f, (void*)enh, pool);
    k_mlp<<<dim3(8), dim3(64), 0, stream>>>(pool, w_g1, b_g1, w_g2, b_g2, gate);
    k_final<<<dim3(512), dim3(256), 0, stream>>>(xb, enh, gate, out);
}

// Round 8
// 202.909 us; speedup vs baseline: 1.1087x; 1.1087x over previous
//
#include <hip/hip_runtime.h>
#include <math.h>

typedef unsigned short u16;
typedef unsigned int   u32;
typedef __attribute__((ext_vector_type(8))) short short8;
typedef __attribute__((ext_vector_type(4))) float f32x4;

#define HW 4096

// ws layout (float offsets). ws_size = 256 MiB.
#define OFS_XB   0ul          // 32768 x 512 bf16: [pixel][ch]; ch 0-255 = x, 256-511 = agg
#define OFS_PD   8388608ul    // 8*9*4096 fp32 partial dot sums (atomic-accumulated)
#define OFS_W1B  8683520ul    // 256x256 bf16 folded embed weights [o][k]
#define OFS_W2B  8716288ul    // 256x512 bf16 folded enhance weights [o][k]
#define OFS_B1   8781824ul    // 256 fp32
#define OFS_B2   8782080ul    // 256 fp32
#define OFS_POOL 8782336ul    // 8*512 fp32 (atomic-accumulated means)
#define OFS_GATE 8786432ul    // 8*256
#define OFS_ENH  8788480ul    // 32768x256 bf16 enhanced

__device__ __forceinline__ u16 f2bf(float x) {
    union { float f; u32 u; } v; v.f = x;
    u32 r = v.u + 0x7fffu + ((v.u >> 16) & 1u);
    return (u16)(r >> 16);
}
__device__ __forceinline__ float bf2f(u16 h) {
    union { u32 u; float f; } v; v.u = ((u32)h) << 16;
    return v.f;
}
__device__ __forceinline__ void ld_g2l_16(u16* l, const u16* g) {
    __builtin_amdgcn_global_load_lds(
        (const __attribute__((address_space(1))) u32*)g,
        (__attribute__((address_space(3))) u32*)l,
        16, 0, 0);
}

// ---------------- cvt (+fused prep): zeros FIRST, then weights, then x->xb ----------------
// ids 0-287: pd zero. 288-291: pool zero. 292-1061: weight fold. 1062-3109: cvt + x-pool.
__global__ __launch_bounds__(256) void k_cvt(
    const float* __restrict__ x, u16* __restrict__ xb, float* __restrict__ pool,
    const float* __restrict__ w1, const float* __restrict__ b1,
    const float* __restrict__ g1, const float* __restrict__ be1,
    const float* __restrict__ m1, const float* __restrict__ v1,
    const float* __restrict__ w2, const float* __restrict__ b2,
    const float* __restrict__ g2, const float* __restrict__ be2,
    const float* __restrict__ m2, const float* __restrict__ v2,
    u16* __restrict__ w1b, u16* __restrict__ w2b,
    float* __restrict__ b1f, float* __restrict__ b2f,
    float* __restrict__ pd)
{
    __shared__ float tile[64][65];
    const int t = threadIdx.x;
    const int id = blockIdx.x;
    if (id < 292) {                          // zeros dispatched before any atomics
        const float4 z = {0.f, 0.f, 0.f, 0.f};
        if (id < 288) ((float4*)(pd + id * 1024))[t] = z;
        else          ((float4*)(pool + (id - 288) * 1024))[t] = z;
        return;
    }
    if (id < 1062) {                         // weight prep
        int idx = (id - 292) * 256 + t;
        if (idx < 65536) {
            int o = idx >> 8;
            float inv = g1[o] * rsqrtf(v1[o] + 1e-5f);
            w1b[idx] = f2bf(w1[idx] * inv);
        } else if (idx < 196608) {
            int j = idx - 65536;
            int o = j >> 9;
            float inv = g2[o] * rsqrtf(v2[o] + 1e-5f);
            w2b[j] = f2bf(w2[j] * inv);
        } else if (idx < 196864) {
            int o = idx - 196608;
            float inv = g1[o] * rsqrtf(v1[o] + 1e-5f);
            b1f[o] = b1[o] * inv + be1[o] - m1[o] * inv;
        } else if (idx < 197120) {
            int o = idx - 196864;
            float inv = g2[o] * rsqrtf(v2[o] + 1e-5f);
            b2f[o] = b2[o] * inv + be2[o] - m2[o] * inv;
        }
        return;
    }
    const int cid = id - 1062;               // 0..2047
    const int pt = cid & 63, ct = (cid >> 6) & 3, b = cid >> 8;
    const float* src = x + (((size_t)(b * 256 + ct * 64)) << 12) + pt * 64;
#pragma unroll
    for (int i = 0; i < 16; ++i) {
        int idx = i * 256 + t;
        int cl = idx >> 6, pl = idx & 63;
        tile[cl][pl] = src[((size_t)cl << 12) + pl];
    }
    __syncthreads();
#pragma unroll
    for (int i = 0; i < 8; ++i) {
        int idx = i * 256 + t;
        int pl = idx >> 5, c2 = idx & 31;
        int cl = c2 * 2;
        u32 lo = f2bf(tile[cl][pl]);
        u32 hi = f2bf(tile[cl + 1][pl]);
        *(u32*)(xb + (((size_t)(b * 4096 + pt * 64 + pl)) << 9) + ct * 64 + cl) = lo | (hi << 16);
    }
    if (t < 64) {
        float s = 0.f;
#pragma unroll
        for (int i = 0; i < 64; ++i) s += tile[t][i];
        atomicAdd(&pool[(b << 9) + ct * 64 + t], s * (1.f / 4096.f));
    }
}

// ---------------- bf16 MFMA GEMM: out = relu(W @ X + bias) [+ fused pool] ----------------
// 1-D grid 512. o=(id>>3)&1, p_tile=((id>>4)<<3)|(id&7): both o-blocks of a
// p-tile land on XCD p_tile%8, 8 dispatch-ids apart -> X tile L2-shared.
template<int KIN, bool OUTBF, bool DOPOOL>
__global__ __launch_bounds__(256) void k_gemm(
    const u16* __restrict__ xb, const u16* __restrict__ Wb,
    const float* __restrict__ biasf, void* __restrict__ outp,
    float* __restrict__ poolp)
{
    __shared__ __align__(16) u16 Wl[4096];
    __shared__ __align__(16) u16 Xl[4096];
    __shared__ float sbias[128];
    const int t = threadIdx.x;
    const int lane = t & 63;
    const int wv = t >> 6;
    const int id = blockIdx.x;
    const int p_blk = (((id >> 4) << 3) | (id & 7)) * 128;
    const int o_blk = ((id >> 3) & 1) * 128;
    const int owg = (wv & 1) * 4;
    const int pwg = (wv >> 1) * 4;
    const int r16 = lane & 15, q = lane >> 4;
    if (t < 128) sbias[t] = biasf[o_blk + t];

    f32x4 acc[4][4];
#pragma unroll
    for (int i = 0; i < 4; ++i)
#pragma unroll
        for (int j = 0; j < 4; ++j) acc[i][j] = (f32x4){0.f, 0.f, 0.f, 0.f};

    for (int kc = 0; kc < KIN / 32; ++kc) {
        const int kk = kc * 32 + q * 8;
#pragma unroll
        for (int s = 0; s < 4; ++s) {
            const int bi = wv * 4 + s;
            const u16* g;
            u16* l;
            if (bi < 8) {
                g = Wb + (size_t)(o_blk + bi * 16 + r16) * KIN + kk;
                l = Wl + bi * 512;
            } else {
                g = xb + (((size_t)(p_blk + (bi - 8) * 16 + r16)) << 9) + kk;
                l = Xl + (bi - 8) * 512;
            }
            ld_g2l_16(l, g);
        }
        __syncthreads();
        short8 af[4], bf[4];
#pragma unroll
        for (int i = 0; i < 4; ++i) af[i] = *(const short8*)(Wl + (owg + i) * 512 + lane * 8);
#pragma unroll
        for (int j = 0; j < 4; ++j) bf[j] = *(const short8*)(Xl + (pwg + j) * 512 + lane * 8);
#pragma unroll
        for (int i = 0; i < 4; ++i)
#pragma unroll
            for (int j = 0; j < 4; ++j)
                acc[i][j] = __builtin_amdgcn_mfma_f32_16x16x32_bf16(af[i], bf[j], acc[i][j], 0, 0, 0);
        __syncthreads();
    }

    float bia[4][4];
#pragma unroll
    for (int i = 0; i < 4; ++i)
#pragma unroll
        for (int r = 0; r < 4; ++r) bia[i][r] = sbias[owg * 16 + i * 16 + q * 4 + r];
    const int bidx = p_blk >> 12;
    const int pin0 = (p_blk & 4095) + pwg * 16 + r16;
#pragma unroll
    for (int i = 0; i < 4; ++i) {
#pragma unroll
        for (int r = 0; r < 4; ++r) {
            const int o = o_blk + owg * 16 + i * 16 + q * 4 + r;
            const size_t rowb = ((size_t)(bidx * 256 + o)) << 12;
            float ps = 0.f;
#pragma unroll
            for (int j = 0; j < 4; ++j) {
                float v = fmaxf(acc[i][j][r] + bia[i][r], 0.f);
                const size_t oi = rowb + pin0 + j * 16;
                ((u16*)outp)[oi] = f2bf(v);
                ps += v;
            }
            if (DOPOOL) {
                ps += __shfl_down(ps, 8, 16);
                ps += __shfl_down(ps, 4, 16);
                ps += __shfl_down(ps, 2, 16);
                ps += __shfl_down(ps, 1, 16);
                if (r16 == 0)
                    atomicAdd(&poolp[(bidx << 9) + 256 + o], ps * (1.f / 4096.f));
            }
        }
    }
}

// ---------------- region dot products (partial over 64-ch group) ----------------
// XCD map: b = id&7 -> each XCD owns one batch; fe[b] (2MB) stays L2-resident.
// np is NOT computed: n_k(p) = dot4(p+off_k) (center-norm plane, k=4).
__global__ __launch_bounds__(256) void k_sim(
    const u16* __restrict__ fe, float* __restrict__ pd)
{
    __shared__ __align__(16) u16 st[3 * 4096];   // [r][c][px]
    __shared__ float red[4][64][9];
    const int t = threadIdx.x;
    const int id = blockIdx.x;
    const int b = id & 7, h = (id >> 3) & 63, g = id >> 9;
    const int rows[3] = {h > 0 ? h - 1 : 0, h, h < 63 ? h + 1 : 63};
    const u16* base = fe + (((size_t)(b * 256 + g * 64)) << 12);
#pragma unroll
    for (int it = 0; it < 6; ++it) {
        const int flat = it * 256 + t;
        const int r = flat >> 9, j = flat & 511;     // j = c*8 + chunk
        const u16* gs = base + ((size_t)(j >> 3) << 12) + rows[r] * 64 + (j & 7) * 8;
        ld_g2l_16(st + r * 4096 + j * 8, gs);
    }
    __syncthreads();
    const int w = t & 63, sl = t >> 6;
    const int wl = w > 0 ? w - 1 : 0, wr = w < 63 ? w + 1 : 63;
    float dot[9] = {};
    const u16* s0 = st + sl * 16 * 64;
#pragma unroll 4
    for (int ci = 0; ci < 16; ++ci) {
        const u16* pc = s0 + ci * 64;
        float v[9];
#pragma unroll
        for (int r = 0; r < 3; ++r) {
            v[r * 3 + 0] = bf2f(pc[r * 4096 + wl]);
            v[r * 3 + 1] = bf2f(pc[r * 4096 + w]);
            v[r * 3 + 2] = bf2f(pc[r * 4096 + wr]);
        }
        const float c0 = v[4];
#pragma unroll
        for (int k = 0; k < 9; ++k) dot[k] = fmaf(c0, v[k], dot[k]);
    }
#pragma unroll
    for (int k = 0; k < 9; ++k) red[sl][w][k] = dot[k];
    __syncthreads();
    if (t < 64) {
        const int p = h * 64 + w;
#pragma unroll
        for (int k = 0; k < 9; ++k) {
            float s = red[0][w][k] + red[1][w][k] + red[2][w][k] + red[3][w][k];
            atomicAdd(&pd[((size_t)(b * 9 + k) << 12) + p], s);
        }
    }
}

// ---------------- softmax (fused) + aggregation; bf16 into xb[:,256:512] ----------------
// XCD map: b = id&7. Stored weight = border_mask * softmax.
__global__ __launch_bounds__(256) void k_agg(
    const u16* __restrict__ xb, const float* __restrict__ pd,
    u16* __restrict__ xbo)
{
    __shared__ __align__(16) u16 xt[3 * 4096];   // [r][px][c]
    __shared__ float ws9[9][64];
    const int t = threadIdx.x;
    const int id = blockIdx.x;
    const int b = id & 7, h = (id >> 3) & 63, g = id >> 9;
    const int rows[3] = {h > 0 ? h - 1 : 0, h, h < 63 ? h + 1 : 63};
    const u16* base = xb + (((size_t)(b * 4096)) << 9) + g * 64;
#pragma unroll
    for (int it = 0; it < 6; ++it) {
        const int flat = it * 256 + t;
        const int r = flat >> 9, j = flat & 511;     // j = px*8 + chunk
        const u16* gs = base + (((size_t)(rows[r] * 64 + (j >> 3))) << 9) + (j & 7) * 8;
        ld_g2l_16(xt + r * 4096 + j * 8, gs);
    }
    if (t < 64) {
        const int w = t;
        const int p = h * 64 + w;
        const float* pb = pd + (((size_t)(b * 9)) << 12);
        const float nc = sqrtf(pb[(4 << 12) + p]);
        float s[9], mk[9];
#pragma unroll
        for (int di = -1; di <= 1; ++di)
#pragma unroll
            for (int dj = -1; dj <= 1; ++dj) {
                const int k = (di + 1) * 3 + (dj + 1);
                const int hn = h + di, wn = w + dj;
                const float mask = (hn >= 0 && hn < 64 && wn >= 0 && wn < 64) ? 1.f : 0.f;
                const int hc = hn < 0 ? 0 : (hn > 63 ? 63 : hn);
                const int wc = wn < 0 ? 0 : (wn > 63 ? 63 : wn);
                const float nk = pb[(4 << 12) + hc * 64 + wc];
                const float dk = pb[(k << 12) + p];
                mk[k] = mask;
                s[k] = mask * dk / (nc * sqrtf(nk) + 1e-7f);
            }
        float mx = s[0];
#pragma unroll
        for (int k = 1; k < 9; ++k) mx = fmaxf(mx, s[k]);
        float e[9], sum = 0.f;
#pragma unroll
        for (int k = 0; k < 9; ++k) { e[k] = expf(s[k] - mx); sum += e[k]; }
        const float rs = 1.f / sum;
#pragma unroll
        for (int k = 0; k < 9; ++k) ws9[k][w] = mk[k] * e[k] * rs;
    }
    __syncthreads();
    const int c = t & 63, pg = t >> 6;   // 16 px per thread, lane = channel
    u16* orow = xbo + (((size_t)(b * 4096 + h * 64)) << 9) + 256 + g * 64 + c;
#pragma unroll 4
    for (int pi = 0; pi < 16; ++pi) {
        const int px = pg * 16 + pi;
        const int pl = px > 0 ? px - 1 : 0, pr = px < 63 ? px + 1 : 63;
        const int pxs[3] = {pl, px, pr};
        float m[9];
#pragma unroll
        for (int k = 0; k < 9; ++k) m[k] = ws9[k][px];
        float acc = 0.f;
#pragma unroll
        for (int r = 0; r < 3; ++r)
#pragma unroll
            for (int j = 0; j < 3; ++j)
                acc = fmaf(bf2f(xt[r * 4096 + pxs[j] * 64 + c]), m[r * 3 + j], acc);
        orow[(size_t)px << 9] = f2bf(acc);
    }
}

// ---------------- SE-style gate MLP (widened: 256 threads) ----------------
__global__ __launch_bounds__(256) void k_mlp(
    const float* __restrict__ pool,
    const float* __restrict__ wg1, const float* __restrict__ bg1,
    const float* __restrict__ wg2, const float* __restrict__ bg2,
    float* __restrict__ gate)
{
    __shared__ float pl[512];
    __shared__ float hpart[4][64];
    __shared__ float hb[64];
    const int b = blockIdx.x, t = threadIdx.x;
    pl[t] = pool[b * 512 + t];
    pl[t + 256] = pool[b * 512 + t + 256];
    __syncthreads();
    const int o = t & 63, seg = t >> 6;
    float s = 0.f;
    const float* wr = wg1 + o * 512 + seg * 128;
    const float* pr = pl + seg * 128;
#pragma unroll 4
    for (int j = 0; j < 128; ++j) s = fmaf(wr[j], pr[j], s);
    hpart[seg][o] = s;
    __syncthreads();
    if (t < 64)
        hb[t] = fmaxf(hpart[0][t] + hpart[1][t] + hpart[2][t] + hpart[3][t] + bg1[t], 0.f);
    __syncthreads();
    float s2 = bg2[t];
    const float* w2 = wg2 + t * 64;
#pragma unroll 4
    for (int j = 0; j < 64; ++j) s2 = fmaf(w2[j], hb[j], s2);
    gate[b * 256 + t] = 1.f / (1.f + expf(-s2));
}

// ---------------- final: out = x(bf16 from xb) + gate * enhanced(bf16) ----------------
// XCD map: b = id&7.
__global__ __launch_bounds__(256) void k_final(
    const u16* __restrict__ xb, const u16* __restrict__ enh,
    const float* __restrict__ gate, float* __restrict__ out)
{
    const int t = threadIdx.x;
    const int id = blockIdx.x;               // 512 = b(8) x 64 groups
    const int b = id & 7, rg = id >> 3;
    const int w = t & 63, s = t >> 6;
    const int p = rg * 64 + w;
    const u16* xrow = xb + (((size_t)(b * 4096 + p)) << 9) + s * 64;
#pragma unroll 2
    for (int cc = 0; cc < 8; ++cc) {
        short8 xv = *(const short8*)(xrow + cc * 8);
#pragma unroll
        for (int u = 0; u < 8; ++u) {
            const int c = s * 64 + cc * 8 + u;
            const float gt = gate[(b << 8) + c];
            const size_t off = (((size_t)(b * 256 + c)) << 12) + p;
            out[off] = fmaf(gt, bf2f(enh[off]), bf2f((u16)xv[u]));
        }
    }
}

extern "C" void kernel_launch(void* const* d_in, const int* in_sizes, int n_in,
                              void* d_out, int out_size, void* d_ws, size_t ws_size,
                              hipStream_t stream)
{
    const float* x       = (const float*)d_in[0];
    const float* w_embed = (const float*)d_in[1];
    const float* b_embed = (const float*)d_in[2];
    const float* g1      = (const float*)d_in[3];
    const float* be1     = (const float*)d_in[4];
    const float* m1      = (const float*)d_in[5];
    const float* v1      = (const float*)d_in[6];
    const float* w_enh   = (const float*)d_in[7];
    const float* b_enh   = (const float*)d_in[8];
    const float* g2      = (const float*)d_in[9];
    const float* be2     = (const float*)d_in[10];
    const float* m2      = (const float*)d_in[11];
    const float* v2      = (const float*)d_in[12];
    const float* w_g1    = (const float*)d_in[13];
    const float* b_g1    = (const float*)d_in[14];
    const float* w_g2    = (const float*)d_in[15];
    const float* b_g2    = (const float*)d_in[16];
    float* ws  = (float*)d_ws;
    float* out = (float*)d_out;

    u16*   xb   = (u16*)(ws + OFS_XB);
    float* pd   = ws + OFS_PD;
    u16*   w1b  = (u16*)(ws + OFS_W1B);
    u16*   w2b  = (u16*)(ws + OFS_W2B);
    float* b1f  = ws + OFS_B1;
    float* b2f  = ws + OFS_B2;
    float* pool = ws + OFS_POOL;
    float* gate = ws + OFS_GATE;
    u16*   enh  = (u16*)(ws + OFS_ENH);
    u16*   fe   = (u16*)d_out;   // fe (bf16) lives in d_out; dead before k_final writes

    k_cvt<<<dim3(3110), dim3(256), 0, stream>>>(
        x, xb, pool,
        w_embed, b_embed, g1, be1, m1, v1,
        w_enh, b_enh, g2, be2, m2, v2, w1b, w2b, b1f, b2f, pd);
    k_gemm<256, true, false><<<dim3(512), dim3(256), 0, stream>>>(xb, w1b, b1f, (void*)fe, nullptr);
    k_sim<<<dim3(2048), dim3(256), 0, stream>>>(fe, pd);
    k_agg<<<dim3(2048), dim3(256), 0, stream>>>(xb, pd, xb);
    k_gemm<512, true, true><<<dim3(512), dim3(256), 0, stream>>>(xb, w2b, b2f, (void*)enh, pool);
    k_mlp<<<dim3(8), dim3(256), 0, stream>>>(pool, w_g1, b_g1, w_g2, b_g2, gate);
    k_final<<<dim3(512), dim3(256), 0, stream>>>(xb, enh, gate, out);
}